// Round 2
// baseline (1679.308 us; speedup 1.0000x reference)
//
#include <hip/hip_runtime.h>
#include <math.h>

#define SS 128
#define BB 32
#define CC 16
#define DW 256
#define DC 64
#define HC 128
#define KX 384   // DW + HC
#define TT 17

typedef __attribute__((ext_vector_type(8))) short bf16x8;
typedef __attribute__((ext_vector_type(4))) float f32x4;
typedef unsigned long long ull_t;

__device__ __forceinline__ float sigf(float x) { return 1.0f / (1.0f + __expf(-x)); }
__device__ __forceinline__ float tanhfast(float x) {
  float xc = fminf(fmaxf(x, -15.f), 15.f);
  float e = __expf(2.f * xc);
  return (e - 1.f) / (e + 1.f);
}
__device__ __forceinline__ unsigned short f2bf(float x) {
  unsigned int u = __float_as_uint(x);
  u += 0x7FFF + ((u >> 16) & 1);
  return (unsigned short)(u >> 16);
}

// ---------------------------------------------------------------- K0: char ih vocab table
__global__ __launch_bounds__(256) void k0_ihvocab(
    const float* __restrict__ Wce,
    const float* __restrict__ WihF, const float* __restrict__ bF,
    const float* __restrict__ WihB, const float* __restrict__ bB,
    float* __restrict__ ihv) {
  int blk = blockIdx.x;          // 0..199
  int d = blk / 100, v = blk % 100;
  const float* Wih = d ? WihB : WihF;
  const float* bb  = d ? bB   : bF;
  __shared__ float ce[DC];
  if (threadIdx.x < DC) ce[threadIdx.x] = Wce[v * DC + threadIdx.x];
  __syncthreads();
  int g = threadIdx.x;
  float acc = bb[g];
  #pragma unroll 16
  for (int k = 0; k < DC; ++k) acc += ce[k] * Wih[g * DC + k];
  ihv[(d * 100 + v) * 256 + g] = acc;
}

// ---------------------------------------------------------------- K1: char BiLSTM (per-chain, no global sync)
__global__ __launch_bounds__(256) void k1_char(
    const int* __restrict__ charidx,   // (B,S,C)
    const float* __restrict__ WhhF, const float* __restrict__ WhhB,
    const float* __restrict__ ihv,     // (2,100,256)
    float* __restrict__ x)             // (4096, 384)
{
  int blk = blockIdx.x;
  int d = blk >> 8;
  int n0 = (blk & 255) * 16;
  const float* Whh = d ? WhhB : WhhF;

  __shared__ float Wl[256 * 68];
  __shared__ float hl[16 * 68];

  for (int i = threadIdx.x; i < 256 * 64; i += 256) {
    int g = i >> 6, k = i & 63;
    Wl[g * 68 + k] = Whh[i];
  }
  __syncthreads();

  int hh = threadIdx.x & 63;
  int ng = threadIdx.x >> 6;
  float c[4] = {0.f, 0.f, 0.f, 0.f};
  float h[4] = {0.f, 0.f, 0.f, 0.f};
  int bb_[4], ss_[4];
  #pragma unroll
  for (int m = 0; m < 4; ++m) {
    int n = n0 + ng + 4 * m;
    bb_[m] = n >> 7; ss_[m] = n & 127;
  }

  for (int t = 0; t < CC; ++t) {
    int cpos = d ? (CC - 1 - t) : t;
    float acc[4][4];
    #pragma unroll
    for (int m = 0; m < 4; ++m) {
      int v = charidx[bb_[m] * (SS * CC) + ss_[m] * CC + cpos];
      const float* base = ihv + (d * 100 + v) * 256 + hh;
      acc[m][0] = base[0]; acc[m][1] = base[64]; acc[m][2] = base[128]; acc[m][3] = base[192];
    }
    if (t > 0) {
      #pragma unroll 4
      for (int k = 0; k < 64; k += 4) {
        float4 w4[4];
        #pragma unroll
        for (int q = 0; q < 4; ++q)
          w4[q] = *(const float4*)&Wl[(q * 64 + hh) * 68 + k];
        #pragma unroll
        for (int m = 0; m < 4; ++m) {
          float4 h4 = *(const float4*)&hl[(ng + 4 * m) * 68 + k];
          #pragma unroll
          for (int q = 0; q < 4; ++q)
            acc[m][q] += h4.x * w4[q].x + h4.y * w4[q].y + h4.z * w4[q].z + h4.w * w4[q].w;
        }
      }
      __syncthreads();
    }
    #pragma unroll
    for (int m = 0; m < 4; ++m) {
      float ig = sigf(acc[m][0]);
      float fg = sigf(acc[m][1]);
      float gg = tanhfast(acc[m][2]);
      float og = sigf(acc[m][3]);
      c[m] = fg * c[m] + ig * gg;
      h[m] = og * tanhfast(c[m]);
      hl[(ng + 4 * m) * 68 + hh] = h[m];
    }
    __syncthreads();
  }
  #pragma unroll
  for (int m = 0; m < 4; ++m) {
    int row = ss_[m] * BB + bb_[m];
    x[row * KX + d * 64 + hh] = h[m];
  }
}

// ---------------------------------------------------------------- K2: word embedding gather
__global__ __launch_bounds__(64) void k2_we(
    const int* __restrict__ sentence, const float* __restrict__ Wwe,
    float* __restrict__ x) {
  int row = blockIdx.x;
  int idx = sentence[row];
  const float4* src = (const float4*)(Wwe + (size_t)idx * DW);
  float4* dst = (float4*)(x + (size_t)row * KX + HC);
  dst[threadIdx.x] = src[threadIdx.x];
}

// ---------------------------------------------------------------- K3: word ih GEMM  wg[d][row][g]
__global__ __launch_bounds__(256) void k3_ihgemm(
    const float* __restrict__ x,
    const float* __restrict__ WihF, const float* __restrict__ bF,
    const float* __restrict__ WihB, const float* __restrict__ bB,
    float* __restrict__ wg) {
  int n0 = blockIdx.x * 128;
  int m0 = blockIdx.y * 128;
  int d  = n0 >> 10;
  int gb = n0 & 1023;
  const float* Wih  = d ? WihB : WihF;
  const float* bias = d ? bB   : bF;

  __shared__ float At[32][132];
  __shared__ float Bt[32][132];

  int tid = threadIdx.x;
  int half = tid & 1, r = tid >> 1;
  int tm = tid & 15, tn = tid >> 4;
  float acc[8][8] = {};

  for (int k0 = 0; k0 < KX; k0 += 32) {
    __syncthreads();
    {
      const float4* srcA = (const float4*)(x + (size_t)(m0 + r) * KX + k0 + half * 16);
      const float4* srcB = (const float4*)(Wih + (size_t)(gb + r) * KX + k0 + half * 16);
      #pragma unroll
      for (int q = 0; q < 4; ++q) {
        float4 v = srcA[q];
        int kk = half * 16 + q * 4;
        At[kk + 0][r] = v.x; At[kk + 1][r] = v.y; At[kk + 2][r] = v.z; At[kk + 3][r] = v.w;
      }
      #pragma unroll
      for (int q = 0; q < 4; ++q) {
        float4 v = srcB[q];
        int kk = half * 16 + q * 4;
        Bt[kk + 0][r] = v.x; Bt[kk + 1][r] = v.y; Bt[kk + 2][r] = v.z; Bt[kk + 3][r] = v.w;
      }
    }
    __syncthreads();
    #pragma unroll 8
    for (int k = 0; k < 32; ++k) {
      float4 a0 = *(const float4*)&At[k][tm * 8];
      float4 a1 = *(const float4*)&At[k][tm * 8 + 4];
      float4 b0 = *(const float4*)&Bt[k][tn * 8];
      float4 b1 = *(const float4*)&Bt[k][tn * 8 + 4];
      float av[8] = {a0.x, a0.y, a0.z, a0.w, a1.x, a1.y, a1.z, a1.w};
      float bv[8] = {b0.x, b0.y, b0.z, b0.w, b1.x, b1.y, b1.z, b1.w};
      #pragma unroll
      for (int i = 0; i < 8; ++i)
        #pragma unroll
        for (int jq = 0; jq < 8; ++jq)
          acc[i][jq] += av[i] * bv[jq];
    }
  }
  float bv8[8];
  #pragma unroll
  for (int jq = 0; jq < 8; ++jq) bv8[jq] = bias[gb + tn * 8 + jq];
  #pragma unroll
  for (int i = 0; i < 8; ++i) {
    int m = m0 + tm * 8 + i;
    float* dst = wg + ((size_t)(d * 4096 + m)) * 1024 + gb + tn * 8;
    float4 v0 = {acc[i][0] + bv8[0], acc[i][1] + bv8[1], acc[i][2] + bv8[2], acc[i][3] + bv8[3]};
    float4 v1 = {acc[i][4] + bv8[4], acc[i][5] + bv8[5], acc[i][6] + bv8[6], acc[i][7] + bv8[7]};
    *(float4*)dst = v0; *(float4*)(dst + 4) = v1;
  }
}

// ---------------------------------------------------------------- K3b: pack streamed Whh quarter (ch=1, ks=4..7) as bf16 frags
// Layout: wstr[((d*8 + w)*16 + q*4 + (ks-4)) * 512 + lane*8] (shorts).
__global__ __launch_bounds__(64) void k3b_pack(
    const float* __restrict__ WhhF, const float* __restrict__ WhhB,
    unsigned short* __restrict__ wstr) {
  int bid = blockIdx.x;            // 0..255
  int d = bid >> 7;
  int rem = bid & 127;             // w*16 + fidx
  int w = rem >> 4, fidx = rem & 15;
  int q = fidx >> 2, ks = (fidx & 3) + 4;
  const float* Whh = d ? WhhB : WhhF;
  int l = threadIdx.x, l15 = l & 15, q4 = l >> 4;
  const float* wr = Whh + (size_t)(q * 256 + w * 32 + 16 + l15) * 256 + ks * 32 + q4 * 8;
  float4 lo = *(const float4*)(wr);
  float4 hi = *(const float4*)(wr + 4);
  bf16x8 f;
  f[0] = (short)f2bf(lo.x); f[1] = (short)f2bf(lo.y);
  f[2] = (short)f2bf(lo.z); f[3] = (short)f2bf(lo.w);
  f[4] = (short)f2bf(hi.x); f[5] = (short)f2bf(hi.y);
  f[6] = (short)f2bf(hi.z); f[7] = (short)f2bf(hi.w);
  *(bf16x8*)(wstr + (size_t)(bid * 512 + l * 8)) = f;
}

// ---------------------------------------------------------------- K4: word BiLSTM recurrence (batch-split, barrier-synced)
// 4 WGs = 2 dir x 2 batch-halves; each WG: 8 waves x 512 thr, owns 16 batches
// and ALL 256 h-cols. Wave w owns cols j0=w*32..+31 x 4 gates (N=128, M=16,
// K=256 -> 64 MFMA 16x16x32 per wave per step). h exchange: LDS + 1 barrier
// per step. Whh per wave (64KB bf16): 32 frags resident VGPR (ch=0), 16 in
// LDS (ch=1 ks0..3), 16 streamed from L2 each step (ch=1 ks4..7, prepacked).
// No atomics, no cross-WG traffic. 147KB LDS/WG -> exclusive CU per WG.
__global__ __launch_bounds__(512, 2) void k4_word(
    const float* __restrict__ WhhF, const float* __restrict__ WhhB,
    const float* __restrict__ wg,           // (2,4096,1024) f32
    float* __restrict__ outh,               // (4096,512) f32
    const unsigned short* __restrict__ wstr) {
  const int blk = blockIdx.x;               // 0..3
  const int d = blk >> 1, half = blk & 1;
  const int tid = threadIdx.x;
  const int w = tid >> 6;                   // wave 0..7
  const int l = tid & 63;
  const int l15 = l & 15, q4 = l >> 4;
  const int j0 = w * 32;
  const float* __restrict__ Whh = d ? WhhB : WhhF;

  __shared__ unsigned short ldsw[8 * 16 * 64 * 8];   // 131072 B: weight frags
  __shared__ unsigned short hsh[2 * 16 * 256];       // 16384 B: h double-buffer (swizzled)

  // ---- resident Bf: ch=0 (cols j0..j0+15), q=0..3, ks=0..7
  bf16x8 Bf[4][8];
  #pragma unroll
  for (int q = 0; q < 4; ++q) {
    const float* wr = Whh + (size_t)(q * 256 + j0 + l15) * 256 + q4 * 8;
    #pragma unroll
    for (int ks = 0; ks < 8; ++ks) {
      float4 lo = *(const float4*)(wr + ks * 32);
      float4 hi = *(const float4*)(wr + ks * 32 + 4);
      bf16x8 f;
      f[0] = (short)f2bf(lo.x); f[1] = (short)f2bf(lo.y);
      f[2] = (short)f2bf(lo.z); f[3] = (short)f2bf(lo.w);
      f[4] = (short)f2bf(hi.x); f[5] = (short)f2bf(hi.y);
      f[6] = (short)f2bf(hi.z); f[7] = (short)f2bf(hi.w);
      Bf[q][ks] = f;
    }
  }
  // ---- LDS weights: ch=1 (cols j0+16..j0+31), ks=0..3 (one-time, wave-own)
  #pragma unroll
  for (int q = 0; q < 4; ++q) {
    const float* wr = Whh + (size_t)(q * 256 + j0 + 16 + l15) * 256 + q4 * 8;
    #pragma unroll
    for (int ks = 0; ks < 4; ++ks) {
      float4 lo = *(const float4*)(wr + ks * 32);
      float4 hi = *(const float4*)(wr + ks * 32 + 4);
      bf16x8 f;
      f[0] = (short)f2bf(lo.x); f[1] = (short)f2bf(lo.y);
      f[2] = (short)f2bf(lo.z); f[3] = (short)f2bf(lo.w);
      f[4] = (short)f2bf(hi.x); f[5] = (short)f2bf(hi.y);
      f[6] = (short)f2bf(hi.z); f[7] = (short)f2bf(hi.w);
      *(bf16x8*)&ldsw[((w * 16 + q * 4 + ks) * 64 + l) * 8] = f;
    }
  }

  const unsigned short* sbase = wstr + (size_t)(d * 8 + w) * 8192;  // 16 frags * 512 shorts

  f32x4 acc[4][2];
  float cst[8];
  #pragma unroll
  for (int i = 0; i < 8; ++i) cst[i] = 0.f;

  // ---- prologue: gates for t=0
  {
    const int s0 = d ? (SS - 1) : 0;
    const float* wgs = wg + ((size_t)d * 4096 + (size_t)s0 * 32 + half * 16) * 1024 + j0 + l15;
    #pragma unroll
    for (int q = 0; q < 4; ++q)
      #pragma unroll
      for (int ch = 0; ch < 2; ++ch)
        #pragma unroll
        for (int r = 0; r < 4; ++r)
          acc[q][ch][r] = wgs[(size_t)(q4 * 4 + r) * 1024 + q * 256 + ch * 16];
  }

  bf16x8 Sb[8];
  for (int t = 0; t < SS; ++t) {
    const int s = d ? (SS - 1 - t) : t;

    if (t > 0) {
      // ---- issue stream chunk A (q=0,1 | ch1 | ks4..7) pre-barrier
      #pragma unroll
      for (int i = 0; i < 8; ++i)
        Sb[i] = *(const bf16x8*)(sbase + i * 512 + l * 8);
      __syncthreads();
      const int pr = ((t - 1) & 1) * 4096;
      // ---- khalf0: Af ks0..3, resident + LDS weights
      bf16x8 Af0[4];
      #pragma unroll
      for (int ks = 0; ks < 4; ++ks)
        Af0[ks] = *(const bf16x8*)&hsh[pr + l15 * 256 + (((ks * 4 + q4) ^ (l15 & 7)) * 8)];
      #pragma unroll
      for (int q = 0; q < 4; ++q) {
        #pragma unroll
        for (int ks = 0; ks < 4; ++ks)
          acc[q][0] = __builtin_amdgcn_mfma_f32_16x16x32_bf16(Af0[ks], Bf[q][ks], acc[q][0], 0, 0, 0);
        #pragma unroll
        for (int ks = 0; ks < 4; ++ks) {
          bf16x8 bw = *(const bf16x8*)&ldsw[((w * 16 + q * 4 + ks) * 64 + l) * 8];
          acc[q][1] = __builtin_amdgcn_mfma_f32_16x16x32_bf16(Af0[ks], bw, acc[q][1], 0, 0, 0);
        }
      }
      // ---- issue stream chunk B (q=2,3 | ch1 | ks4..7); hidden under khalf1
      bf16x8 Sb2[8];
      #pragma unroll
      for (int i = 0; i < 8; ++i)
        Sb2[i] = *(const bf16x8*)(sbase + (8 + i) * 512 + l * 8);
      // ---- khalf1: Af ks4..7, resident + streamed
      bf16x8 Af1[4];
      #pragma unroll
      for (int ks = 0; ks < 4; ++ks)
        Af1[ks] = *(const bf16x8*)&hsh[pr + l15 * 256 + ((((ks + 4) * 4 + q4) ^ (l15 & 7)) * 8)];
      #pragma unroll
      for (int q = 0; q < 4; ++q)
        #pragma unroll
        for (int ks = 0; ks < 4; ++ks)
          acc[q][0] = __builtin_amdgcn_mfma_f32_16x16x32_bf16(Af1[ks], Bf[q][ks + 4], acc[q][0], 0, 0, 0);
      #pragma unroll
      for (int q = 0; q < 2; ++q)
        #pragma unroll
        for (int kk = 0; kk < 4; ++kk)
          acc[q][1] = __builtin_amdgcn_mfma_f32_16x16x32_bf16(Af1[kk], Sb[q * 4 + kk], acc[q][1], 0, 0, 0);
      #pragma unroll
      for (int q = 2; q < 4; ++q)
        #pragma unroll
        for (int kk = 0; kk < 4; ++kk)
          acc[q][1] = __builtin_amdgcn_mfma_f32_16x16x32_bf16(Af1[kk], Sb2[(q - 2) * 4 + kk], acc[q][1], 0, 0, 0);
    }

    // ---- activations; lane owns (b = half*16 + q4*4+r, col = j0 + ch*16 + l15)
    float hv[8];
    #pragma unroll
    for (int ch = 0; ch < 2; ++ch)
      #pragma unroll
      for (int r = 0; r < 4; ++r) {
        int ix = ch * 4 + r;
        float ig = sigf(acc[0][ch][r]);
        float fg = sigf(acc[1][ch][r]);
        float gg = tanhfast(acc[2][ch][r]);
        float og = sigf(acc[3][ch][r]);
        float c2 = fg * cst[ix] + ig * gg;
        cst[ix] = c2;
        hv[ix] = og * tanhfast(c2);
      }

    // ---- gates for t+1 (issued early; HBM latency hides under barrier+Af+MFMA)
    if (t < SS - 1) {
      const int sn = d ? (SS - 2 - t) : (t + 1);
      const float* wgs = wg + ((size_t)d * 4096 + (size_t)sn * 32 + half * 16) * 1024 + j0 + l15;
      #pragma unroll
      for (int q = 0; q < 4; ++q)
        #pragma unroll
        for (int ch = 0; ch < 2; ++ch)
          #pragma unroll
          for (int r = 0; r < 4; ++r)
            acc[q][ch][r] = wgs[(size_t)(q4 * 4 + r) * 1024 + q * 256 + ch * 16];
    }

    // ---- publish h_t to LDS (swizzled: 16B-unit ^= row&7)
    {
      const int p = (t & 1) * 4096;
      #pragma unroll
      for (int ch = 0; ch < 2; ++ch)
        #pragma unroll
        for (int r = 0; r < 4; ++r) {
          int b = q4 * 4 + r;
          int col = j0 + ch * 16 + l15;
          hsh[p + b * 256 + (((col >> 3) ^ (b & 7)) * 8) + (col & 7)] = f2bf(hv[ch * 4 + r]);
        }
    }

    // ---- outh (non-temporal, off critical path)
    {
      float* op = outh + ((size_t)(s * 32 + half * 16)) * 512 + d * 256 + j0 + l15;
      #pragma unroll
      for (int ch = 0; ch < 2; ++ch)
        #pragma unroll
        for (int r = 0; r < 4; ++r)
          __builtin_nontemporal_store(hv[ch * 4 + r], op + (size_t)(q4 * 4 + r) * 512 + ch * 16);
    }
  }
}

// ---------------------------------------------------------------- K5: emit GEMM (tiny)
__global__ __launch_bounds__(64) void k5_emit(
    const float* __restrict__ outh, const float* __restrict__ eW,
    const float* __restrict__ eb, float* __restrict__ em) {
  int row = blockIdx.x;
  int t = threadIdx.x;
  if (t < TT) {
    const float4* o4 = (const float4*)(outh + (size_t)row * 512);
    const float4* w4 = (const float4*)(eW + (size_t)t * 512);
    float acc = 0.f;
    #pragma unroll 16
    for (int k = 0; k < 128; ++k) {
      float4 a = o4[k], bq = w4[k];
      acc += a.x * bq.x + a.y * bq.y + a.z * bq.z + a.w * bq.w;
    }
    em[row * TT + t] = acc + eb[t];
  }
}

// ---------------------------------------------------------------- K6: CRF NLL (32 independent batches)
__global__ __launch_bounds__(64) void k6_crf(
    const int* __restrict__ sentence, const int* __restrict__ tags,
    const float* __restrict__ em, const float* __restrict__ trans,
    const float* __restrict__ startv, const float* __restrict__ endv,
    float* __restrict__ outp) {
  int b = blockIdx.x;
  int j = threadIdx.x;
  __shared__ float ash[TT];
  __shared__ float red[TT];
  float tc[TT];
  float alpha = 0.f;
  if (j < TT) {
    #pragma unroll
    for (int i = 0; i < TT; ++i) tc[i] = trans[i * TT + j];
    alpha = startv[j] + em[(0 * BB + b) * TT + j];
  }
  for (int s = 1; s < SS; ++s) {
    if (j < TT) ash[j] = alpha;
    __syncthreads();
    int m = (sentence[s * BB + b] != 1) ? 1 : 0;
    if (j < TT) {
      float mx = -1e30f;
      #pragma unroll
      for (int i = 0; i < TT; ++i) mx = fmaxf(mx, ash[i] + tc[i]);
      float sum = 0.f;
      #pragma unroll
      for (int i = 0; i < TT; ++i) sum += __expf(ash[i] + tc[i] - mx);
      float nxt = mx + __logf(sum) + em[(s * BB + b) * TT + j];
      if (m) alpha = nxt;
    }
    __syncthreads();
  }
  if (j < TT) red[j] = alpha + endv[j];
  __syncthreads();
  if (j == 0) {
    float mx = -1e30f;
    for (int i = 0; i < TT; ++i) mx = fmaxf(mx, red[i]);
    float sum = 0.f;
    for (int i = 0; i < TT; ++i) sum += __expf(red[i] - mx);
    float den = mx + __logf(sum);
    int prev = tags[0 * BB + b];
    float num = startv[prev] + em[(0 * BB + b) * TT + prev];
    for (int s = 1; s < SS; ++s) {
      int tg = tags[s * BB + b];
      if (sentence[s * BB + b] != 1) {
        num += trans[prev * TT + tg] + em[(s * BB + b) * TT + tg];
        prev = tg;
      }
    }
    num += endv[prev];
    atomicAdd(outp, den - num);
  }
}

// ---------------------------------------------------------------- launcher
extern "C" void kernel_launch(void* const* d_in, const int* in_sizes, int n_in,
                              void* d_out, int out_size, void* d_ws, size_t ws_size,
                              hipStream_t stream) {
  (void)in_sizes; (void)n_in; (void)out_size; (void)ws_size;
  const int*   sentence = (const int*)d_in[0];
  const int*   charidx  = (const int*)d_in[1];
  const int*   tags     = (const int*)d_in[2];
  const float* Wwe   = (const float*)d_in[3];
  const float* Wce   = (const float*)d_in[4];
  const float* cWihF = (const float*)d_in[5];
  const float* cWhhF = (const float*)d_in[6];
  const float* cbF   = (const float*)d_in[7];
  const float* wWihF = (const float*)d_in[8];
  const float* wWhhF = (const float*)d_in[9];
  const float* wbF   = (const float*)d_in[10];
  const float* cWihB = (const float*)d_in[11];
  const float* cWhhB = (const float*)d_in[12];
  const float* cbB   = (const float*)d_in[13];
  const float* wWihB = (const float*)d_in[14];
  const float* wWhhB = (const float*)d_in[15];
  const float* wbB   = (const float*)d_in[16];
  const float* eW    = (const float*)d_in[17];
  const float* eb    = (const float*)d_in[18];
  const float* trans = (const float*)d_in[19];
  const float* startv= (const float*)d_in[20];
  const float* endv  = (const float*)d_in[21];

  char* ws = (char*)d_ws;
  float*          ihv   = (float*)(ws + 512);             //  204800 B
  float*          x     = (float*)(ws + 205312);          // 6291456 B
  float*          wg    = (float*)(ws + 6496768);         // 33554432 B
  float*          outh  = (float*)(ws + 40116736);        // 8388608 B
  float*          em    = (float*)(ws + 48505344);        //  278528 B
  // wstr (262144 B) aliases the head of the em region: em is written only by
  // k5 (after k4 completes), so the packed stream-weight buffer is dead by then.
  unsigned short* wstr  = (unsigned short*)(ws + 48505344);
  // total ws usage: 48,783,872 B (unchanged)

  hipMemsetAsync(d_out, 0, sizeof(float), stream);

  k3b_pack<<<256, 64, 0, stream>>>(wWhhF, wWhhB, wstr);
  k0_ihvocab<<<200, 256, 0, stream>>>(Wce, cWihF, cbF, cWihB, cbB, ihv);
  k1_char<<<512, 256, 0, stream>>>(charidx, cWhhF, cWhhB, ihv, x);
  k2_we<<<4096, 64, 0, stream>>>(sentence, Wwe, x);
  k3_ihgemm<<<dim3(16, 32), 256, 0, stream>>>(x, wWihF, wbF, wWihB, wbB, wg);
  k4_word<<<4, 512, 0, stream>>>(wWhhF, wWhhB, wg, outh, wstr);
  k5_emit<<<4096, 64, 0, stream>>>(outh, eW, eb, em);
  k6_crf<<<32, 64, 0, stream>>>(sentence, tags, em, trans, startv, endv, (float*)d_out);
}